// Round 1
// baseline (208.226 us; speedup 1.0000x reference)
//
#include <hip/hip_runtime.h>

#define G 128

// ---------------------------------------------------------------------------
// Kernel A: fused conv1 (3x3x3, 1->16, SAME) + relu + m0-mask + 2x maxpool.
// Also emits m1 (pooled mask) at 64^3.
// Block (8,8,8)=512 threads: each thread = one pooled voxel (16 channels).
// Grid (8,8,16): x=bx, y=by, z=b*8+bz.  LDS: 18^3 tile of xm + m0 bytes.
// ---------------------------------------------------------------------------
__global__ __launch_bounds__(512)
void k_conv1_pool(const float* __restrict__ x, const int* __restrict__ occ,
                  const float* __restrict__ W1,
                  float* __restrict__ h1p, float* __restrict__ m1)
{
    __shared__ float         sx[18 * 18 * 18];
    __shared__ unsigned char sm[18 * 18 * 18];

    const int bx = blockIdx.x, by = blockIdx.y;
    const int b  = blockIdx.z >> 3, bz = blockIdx.z & 7;
    const int tid = threadIdx.x + threadIdx.y * 8 + threadIdx.z * 64;

    // input tile origin (conv region is 16^3 at (16bz,16by,16bx); halo 1)
    const int z0 = bz * 16 - 1, y0 = by * 16 - 1, x0 = bx * 16 - 1;
    const int base_b = b * G * G * G;

    for (int i = tid; i < 18 * 18 * 18; i += 512) {
        int lz = i / 324, r = i % 324, ly = r / 18, lx = r % 18;
        int gz = z0 + lz, gy = y0 + ly, gx = x0 + lx;
        float v = 0.f; unsigned char mm = 0;
        if ((unsigned)gz < (unsigned)G && (unsigned)gy < (unsigned)G &&
            (unsigned)gx < (unsigned)G) {
            int gi = base_b + (gz * G + gy) * G + gx;
            mm = (occ[gi] == 0) ? 1 : 0;
            v  = mm ? x[gi] : 0.f;
        }
        sx[i] = v; sm[i] = mm;
    }
    __syncthreads();

    const int tx = threadIdx.x, ty = threadIdx.y, tz = threadIdx.z;

    float best[16];
    #pragma unroll
    for (int c = 0; c < 16; ++c) best[c] = 0.f;
    int anym = 0;

    for (int pos = 0; pos < 8; ++pos) {
        int dz = pos >> 2, dy = (pos >> 1) & 1, dx = pos & 1;
        int cz = 2 * tz + dz, cy = 2 * ty + dy, cx = 2 * tx + dx; // conv-local 0..15
        // center voxel in LDS coords = conv coord + 1
        if (sm[((cz + 1) * 18 + (cy + 1)) * 18 + (cx + 1)]) {
            anym = 1;
            float acc[16];
            #pragma unroll
            for (int c = 0; c < 16; ++c) acc[c] = 0.f;
            for (int kz = 0; kz < 3; ++kz)
            for (int ky = 0; ky < 3; ++ky)
            #pragma unroll
            for (int kx = 0; kx < 3; ++kx) {
                float v = sx[((cz + kz) * 18 + (cy + ky)) * 18 + (cx + kx)];
                if (v != 0.f) {     // xm is ~10% dense: skip zero taps
                    const float* w = &W1[((kz * 3 + ky) * 3 + kx) * 16];
                    #pragma unroll
                    for (int c = 0; c < 16; ++c) acc[c] += v * w[c];
                }
            }
            #pragma unroll
            for (int c = 0; c < 16; ++c) {
                float r = acc[c] > 0.f ? acc[c] : 0.f;
                best[c] = best[c] > r ? best[c] : r;
            }
        }
    }

    const int pz = bz * 8 + tz, py = by * 8 + ty, px = bx * 8 + tx;
    const int vidx = ((b * 64 + pz) * 64 + py) * 64 + px;
    float4* o = (float4*)&h1p[vidx * 16];
    o[0] = make_float4(best[0],  best[1],  best[2],  best[3]);
    o[1] = make_float4(best[4],  best[5],  best[6],  best[7]);
    o[2] = make_float4(best[8],  best[9],  best[10], best[11]);
    o[3] = make_float4(best[12], best[13], best[14], best[15]);
    m1[vidx] = anym ? 1.f : 0.f;
}

// ---------------------------------------------------------------------------
// Kernel B: fused conv2 (3x3x3, 16->4, SAME at 64^3) + relu + m1-mask + pool.
// Also emits m2 at 32^3. One thread per pooled voxel; loops the 4^3 input
// voxels and scatter-accumulates into the 8 conv-position accumulators
// (each 16-ch load shared by up to 8 positions).
// Grid (4,32,2) x block 256: px=t&31, py=bx*8+(t>>5), pz=by, b=bz.
// ---------------------------------------------------------------------------
__global__ __launch_bounds__(256)
void k_conv2_pool(const float* __restrict__ h1p, const float* __restrict__ m1,
                  const float* __restrict__ W2,
                  float* __restrict__ h2, float* __restrict__ m2)
{
    const int tid = threadIdx.x;
    const int px = tid & 31;
    const int py = blockIdx.x * 8 + (tid >> 5);
    const int pz = blockIdx.y;
    const int b  = blockIdx.z;

    float acc[8][4];
    #pragma unroll
    for (int p = 0; p < 8; ++p)
        #pragma unroll
        for (int co = 0; co < 4; ++co) acc[p][co] = 0.f;

    for (int iz = 0; iz < 4; ++iz) {
        int gz = 2 * pz - 1 + iz;
        if ((unsigned)gz >= 64u) continue;
        for (int iy = 0; iy < 4; ++iy) {
            int gy = 2 * py - 1 + iy;
            if ((unsigned)gy >= 64u) continue;
            for (int ix = 0; ix < 4; ++ix) {
                int gx = 2 * px - 1 + ix;
                if ((unsigned)gx >= 64u) continue;
                const float4* p4 = (const float4*)&h1p[(((b * 64 + gz) * 64 + gy) * 64 + gx) * 16];
                float4 f0 = p4[0], f1 = p4[1], f2 = p4[2], f3 = p4[3];
                float ch[16] = {f0.x, f0.y, f0.z, f0.w, f1.x, f1.y, f1.z, f1.w,
                                f2.x, f2.y, f2.z, f2.w, f3.x, f3.y, f3.z, f3.w};
                #pragma unroll
                for (int dz = 0; dz < 2; ++dz) {
                    int kz = iz - dz;
                    if ((unsigned)kz > 2u) continue;
                    #pragma unroll
                    for (int dy = 0; dy < 2; ++dy) {
                        int ky = iy - dy;
                        if ((unsigned)ky > 2u) continue;
                        #pragma unroll
                        for (int dx = 0; dx < 2; ++dx) {
                            int kx = ix - dx;
                            if ((unsigned)kx > 2u) continue;
                            const float* w = W2 + ((kz * 3 + ky) * 3 + kx) * 64;
                            #pragma unroll
                            for (int ci = 0; ci < 16; ++ci) {
                                float v = ch[ci];
                                #pragma unroll
                                for (int co = 0; co < 4; ++co)
                                    acc[dz * 4 + dy * 2 + dx][co] += v * w[ci * 4 + co];
                            }
                        }
                    }
                }
            }
        }
    }

    float best[4] = {0.f, 0.f, 0.f, 0.f};
    float mm2 = 0.f;
    #pragma unroll
    for (int dz = 0; dz < 2; ++dz)
    #pragma unroll
    for (int dy = 0; dy < 2; ++dy)
    #pragma unroll
    for (int dx = 0; dx < 2; ++dx) {
        int cz = 2 * pz + dz, cy = 2 * py + dy, cx = 2 * px + dx;
        float mv = m1[((b * 64 + cz) * 64 + cy) * 64 + cx];
        mm2 = fmaxf(mm2, mv);
        int p = dz * 4 + dy * 2 + dx;
        #pragma unroll
        for (int co = 0; co < 4; ++co) {
            float r = acc[p][co] > 0.f ? acc[p][co] : 0.f;
            best[co] = fmaxf(best[co], r * mv);
        }
    }
    const int oidx = ((b * 32 + pz) * 32 + py) * 32 + px;
    *(float4*)&h2[oidx * 4] = make_float4(best[0], best[1], best[2], best[3]);
    m2[oidx] = mm2;
}

// ---------------------------------------------------------------------------
// Kernel C: fused decoder. tconv1(2^3 s2, 4->16)+relu+m3 then
// tconv2(2^3 s2, 16->1)+sigmoid+m4.  JAX conv_transpose flips the kernel:
// out[2i+a] = x[i] * W[1-a].  m3/m4 for all 64 children of a 32^3 parent
// equal m2[parent].  One thread per parent voxel -> 16 float4 stores.
// ---------------------------------------------------------------------------
__global__ __launch_bounds__(256)
void k_decoder(const float* __restrict__ h2, const float* __restrict__ m2,
               const float* __restrict__ Wt1, const float* __restrict__ Wt2,
               float* __restrict__ out)
{
    const int t = blockIdx.x * 256 + threadIdx.x;   // 0..65535
    const int px = t & 31;
    const int py = (t >> 5) & 31;
    const int pz = (t >> 10) & 31;
    const int b  = t >> 15;
    const int pidx = ((b * 32 + pz) * 32 + py) * 32 + px;

    const float m = m2[pidx];
    const float4 hv = *(const float4*)&h2[pidx * 4];

    #pragma unroll
    for (int a = 0; a < 2; ++a) {
        #pragma unroll
        for (int bb = 0; bb < 2; ++bb) {
            // th1 at 64^3 voxel (2pz+a, 2py+bb, 2px+c), c=0,1.
            // weights Wt1[1-a][1-bb][1-c][ci][ch]
            float t0[16], t1[16];
            const int base0 = ((((1 - a) * 2 + (1 - bb)) * 2 + 1) * 4) * 16; // c=0
            const int base1 = ((((1 - a) * 2 + (1 - bb)) * 2 + 0) * 4) * 16; // c=1
            #pragma unroll
            for (int ch = 0; ch < 16; ++ch) {
                float s0 = hv.x * Wt1[base0 + ch]      + hv.y * Wt1[base0 + 16 + ch]
                         + hv.z * Wt1[base0 + 32 + ch] + hv.w * Wt1[base0 + 48 + ch];
                float s1 = hv.x * Wt1[base1 + ch]      + hv.y * Wt1[base1 + 16 + ch]
                         + hv.z * Wt1[base1 + 32 + ch] + hv.w * Wt1[base1 + 48 + ch];
                t0[ch] = s0 > 0.f ? s0 : 0.f;
                t1[ch] = s1 > 0.f ? s1 : 0.f;
            }
            #pragma unroll
            for (int e = 0; e < 2; ++e) {
                #pragma unroll
                for (int f = 0; f < 2; ++f) {
                    const int d = 4 * pz + 2 * a + e;
                    const int h = 4 * py + 2 * bb + f;
                    const int base_ef = ((1 - e) * 2 + (1 - f)) * 2;
                    const float* wg0 = Wt2 + (base_ef + 1) * 16;  // g=0 -> kg=1
                    const float* wg1 = Wt2 + (base_ef + 0) * 16;  // g=1 -> kg=0
                    float s00 = 0.f, s01 = 0.f, s10 = 0.f, s11 = 0.f;
                    #pragma unroll
                    for (int ch = 0; ch < 16; ++ch) {
                        s00 += t0[ch] * wg0[ch];   // c=0,g=0
                        s01 += t0[ch] * wg1[ch];   // c=0,g=1
                        s10 += t1[ch] * wg0[ch];   // c=1,g=0
                        s11 += t1[ch] * wg1[ch];   // c=1,g=1
                    }
                    float4 o;
                    o.x = m / (1.f + __expf(-s00));
                    o.y = m / (1.f + __expf(-s01));
                    o.z = m / (1.f + __expf(-s10));
                    o.w = m / (1.f + __expf(-s11));
                    *(float4*)&out[((b * G + d) * G + h) * G + 4 * px] = o;
                }
            }
        }
    }
}

extern "C" void kernel_launch(void* const* d_in, const int* in_sizes, int n_in,
                              void* d_out, int out_size, void* d_ws, size_t ws_size,
                              hipStream_t stream) {
    (void)in_sizes; (void)n_in; (void)out_size; (void)ws_size;
    const float* x   = (const float*)d_in[0];
    const float* W1  = (const float*)d_in[1];
    const float* W2  = (const float*)d_in[2];
    const float* Wt1 = (const float*)d_in[3];
    const float* Wt2 = (const float*)d_in[4];
    const int*   occ = (const int*)d_in[5];
    float* out = (float*)d_out;

    float* ws  = (float*)d_ws;
    float* h1p = ws;                          // 2*64^3*16 = 8388608 floats
    float* m1  = h1p + 2 * 64 * 64 * 64 * 16; // 2*64^3   =  524288 floats
    float* h2  = m1  + 2 * 64 * 64 * 64;      // 2*32^3*4 =  262144 floats
    float* m2v = h2  + 2 * 32 * 32 * 32 * 4;  // 2*32^3   =   65536 floats
    // total ~37 MB of workspace

    k_conv1_pool<<<dim3(8, 8, 16), dim3(8, 8, 8), 0, stream>>>(x, occ, W1, h1p, m1);
    k_conv2_pool<<<dim3(4, 32, 2), dim3(256), 0, stream>>>(h1p, m1, W2, h2, m2v);
    k_decoder<<<dim3(256), dim3(256), 0, stream>>>(h2, m2v, Wt1, Wt2, out);
}